// Round 7
// baseline (478.927 us; speedup 1.0000x reference)
//
#include <hip/hip_runtime.h>
#include <cstdint>
#include <cstddef>

// ---------------------------------------------------------------------------
// EncoderLayer: x -> QKV -> MHA (flash) -> Wo + resid -> LN1 -> FFN(gelu) -> LN2
// S=2048 B=4 E=768 F=3072 H=12 Dh=64, M = S*B = 8192 tokens.
// R7: persistent-tile GEMM (3-stage vmcnt pipeline runs continuously across
//     output tiles -> per-tile prologue/epilogue overlapped); LN1 bf16-only
//     (y1f fp32 round-trip removed); 7 prep dispatches fused into prep_all.
// ---------------------------------------------------------------------------

typedef unsigned short u16;
typedef __bf16 bf16x8 __attribute__((ext_vector_type(8)));
typedef __bf16 bf16x4 __attribute__((ext_vector_type(4)));
typedef short  s16x4  __attribute__((ext_vector_type(4)));
typedef float  f32x4  __attribute__((ext_vector_type(4)));

#define SCALE_Q 0.18033688011112042f   // 0.125 * log2(e)

__device__ __forceinline__ unsigned fbits(float f) { union { float f; unsigned u; } v; v.f = f; return v.u; }
__device__ __forceinline__ u16 f2bf_fast(float f) { return (u16)((fbits(f) + 0x8000u) >> 16); }
__device__ __forceinline__ float bf2f(u16 u) { union { unsigned u; float f; } v; v.u = (unsigned)u << 16; return v.f; }
__device__ __forceinline__ unsigned pk_rne(float a, float b) {
    return __builtin_amdgcn_perm(fbits(b) + 0x8000u, fbits(a) + 0x8000u, 0x07060302u);
}
__device__ __forceinline__ unsigned pk_trunc(float a, float b) {
    return __builtin_amdgcn_perm(fbits(b), fbits(a), 0x07060302u);
}
__device__ __forceinline__ float exp2f_fast(float x) {
#if __has_builtin(__builtin_amdgcn_exp2f)
    return __builtin_amdgcn_exp2f(x);
#else
    return __expf(x * 0.69314718055994531f);
#endif
}

template <class T, class F>
__device__ __forceinline__ T bc(F f) { union { F a; T b; } u; u.a = f; return u.b; }

__device__ __forceinline__ f32x4 mfma16(s16x4 a, s16x4 b, f32x4 c) {
#if __has_builtin(__builtin_amdgcn_mfma_f32_16x16x16_bf16)
    return __builtin_amdgcn_mfma_f32_16x16x16_bf16(
        __builtin_bit_cast(bf16x4, a), __builtin_bit_cast(bf16x4, b), c, 0, 0, 0);
#else
    return __builtin_amdgcn_mfma_f32_16x16x16bf16_1k(a, b, c, 0, 0, 0);
#endif
}

__device__ __forceinline__ void g2l16(const void* g, void* l) {
    __builtin_amdgcn_global_load_lds(
        (const __attribute__((address_space(1))) unsigned int*)(uintptr_t)g,
        (__attribute__((address_space(3))) unsigned int*)(unsigned int)(uintptr_t)l,
        16, 0, 0);
}

// barrier with bounded vmcnt: newest N global ops may stay in flight.
template <int N>
__device__ __forceinline__ void waitcnt_barrier() {
    if constexpr (N == 0)
        asm volatile("s_waitcnt vmcnt(0) lgkmcnt(0)\ns_barrier" ::: "memory");
    else if constexpr (N == 3)
        asm volatile("s_waitcnt vmcnt(3) lgkmcnt(0)\ns_barrier" ::: "memory");
    else if constexpr (N == 4)
        asm volatile("s_waitcnt vmcnt(4) lgkmcnt(0)\ns_barrier" ::: "memory");
    else
        asm volatile("s_waitcnt vmcnt(6) lgkmcnt(0)\ns_barrier" ::: "memory");
}

// ---------------------------------------------------------------------------
// prep_all: 5 weight transposes (fp32 [Kd][Nd] -> bf16 [Nd][Kd]) + x cvt,
// one dispatch. Blocks 0..6911: transpose tiles; 6912..13055: x cvt.
// ---------------------------------------------------------------------------
__global__ __launch_bounds__(256) void prep_all(const float* __restrict__ x, u16* __restrict__ xbf,
                                                const float* __restrict__ Wq, const float* __restrict__ Wk,
                                                const float* __restrict__ Wv, const float* __restrict__ Wo,
                                                const float* __restrict__ W1, const float* __restrict__ W2,
                                                u16* __restrict__ WqkvT, u16* __restrict__ WoT,
                                                u16* __restrict__ W1T, u16* __restrict__ W2T) {
    const int id = blockIdx.x;
    if (id >= 6912) {                      // x: fp32 -> bf16, 6144 blocks
        int i = (id - 6912) * 256 + threadIdx.x;
        float4 v = ((const float4*)x)[i];
        ((uint2*)xbf)[i] = make_uint2(pk_rne(v.x, v.y), pk_rne(v.z, v.w));
        return;
    }
    const float* src; u16* dst; int Kd, Nd, bx, by, l;
    if (id < 576)       { src = Wq; dst = WqkvT;             Kd = 768;  Nd = 768;  l = id;        bx = l % 24; by = l / 24; }
    else if (id < 1152) { src = Wk; dst = WqkvT + 768 * 768; Kd = 768;  Nd = 768;  l = id - 576;  bx = l % 24; by = l / 24; }
    else if (id < 1728) { src = Wv; dst = WqkvT + 1536 * 768;Kd = 768;  Nd = 768;  l = id - 1152; bx = l % 24; by = l / 24; }
    else if (id < 2304) { src = Wo; dst = WoT;               Kd = 768;  Nd = 768;  l = id - 1728; bx = l % 24; by = l / 24; }
    else if (id < 4608) { src = W1; dst = W1T;               Kd = 768;  Nd = 3072; l = id - 2304; bx = l % 96; by = l / 96; }
    else                { src = W2; dst = W2T;               Kd = 3072; Nd = 768;  l = id - 4608; bx = l % 24; by = l / 24; }
    __shared__ float t[32][33];
    const int k0 = by * 32, n0 = bx * 32;
    const int tx = threadIdx.x & 31, ty = threadIdx.x >> 5;
#pragma unroll
    for (int i = 0; i < 32; i += 8)
        t[ty + i][tx] = src[(size_t)(k0 + ty + i) * Nd + n0 + tx];
    __syncthreads();
#pragma unroll
    for (int i = 0; i < 32; i += 8)
        dst[(size_t)(n0 + ty + i) * Kd + k0 + tx] = f2bf_fast(t[tx][ty + i]);
}

// ---------------------------------------------------------------------------
// build VT[bh][d][s] (bf16) from v [m = s*4+b][h*64+d]
// ---------------------------------------------------------------------------
__global__ __launch_bounds__(256) void build_vt(const u16* __restrict__ v,
                                                u16* __restrict__ vt) {
    __shared__ u16 t[64][65];
    const int bh = blockIdx.y, b = bh / 12, h = bh % 12;
    const int s0 = blockIdx.x * 64;
    const int tid = threadIdx.x;
#pragma unroll
    for (int i = 0; i < 16; i++) {
        int c = i * 256 + tid; int r = c >> 6, d = c & 63;
        t[r][d] = v[((size_t)((s0 + r) * 4 + b)) * 768 + h * 64 + d];
    }
    __syncthreads();
#pragma unroll
    for (int i = 0; i < 16; i++) {
        int c = i * 256 + tid; int dr = c >> 6, s = c & 63;
        vt[((size_t)(bh * 64 + dr)) * 2048 + s0 + s] = t[s][dr];
    }
}

// ---------------------------------------------------------------------------
// LayerNorm over E=768. One block (256 thr) per row.
// ---------------------------------------------------------------------------
__global__ __launch_bounds__(256) void ln_kernel(const float* __restrict__ in,
                                                 const float* __restrict__ gw,
                                                 const float* __restrict__ bw,
                                                 float* __restrict__ of32,
                                                 u16* __restrict__ obf) {
    const int row = blockIdx.x;
    const int tid = threadIdx.x;
    const int lane = tid & 63, w = tid >> 6;
    const float* xr = in + (size_t)row * 768;
    float v0 = xr[tid], v1 = xr[tid + 256], v2 = xr[tid + 512];
    float s = v0 + v1 + v2;
    float s2 = v0 * v0 + v1 * v1 + v2 * v2;
#pragma unroll
    for (int o = 32; o > 0; o >>= 1) { s += __shfl_down(s, o); s2 += __shfl_down(s2, o); }
    __shared__ float red[8];
    if (lane == 0) { red[w] = s; red[4 + w] = s2; }
    __syncthreads();
    s  = red[0] + red[1] + red[2] + red[3];
    s2 = red[4] + red[5] + red[6] + red[7];
    const float mean = s * (1.0f / 768.0f);
    const float rstd = rsqrtf(s2 * (1.0f / 768.0f) - mean * mean + 1e-5f);
    float va[3] = { v0, v1, v2 };
#pragma unroll
    for (int i = 0; i < 3; i++) {
        int j = tid + i * 256;
        float y = (va[i] - mean) * rstd * gw[j] + bw[j];
        if (of32) of32[(size_t)row * 768 + j] = y;
        if (obf)  obf [(size_t)row * 768 + j] = f2bf_fast(y);
    }
}

// ---------------------------------------------------------------------------
// GEMM v5 (persistent tiles): C[M,N] = A[M,K] * Bt[N,K]^T, bf16 in, fp32 acc.
// 1-D grid of persistent blocks; each processes tiles t = bid, bid+nb, ...
// The 3-stage LDS pipeline (vmcnt(PF) barriers) runs CONTINUOUSLY across
// tile boundaries: staging cursor (sTile,sKi) leads the compute cursor by 2
// chunks, so the next tile's first loads are in flight during the previous
// tile's last MFMAs + epilogue. Grid strides are multiples of 8 -> each
// block keeps t%8 == bid%8 (XCD pinned row-groups, B-tiles L2-resident).
// MODE 0: QKV -> q=(v+bq)*SCALE_Q / k=v+bk / v=v+bv, bf16 out [m][768] each
// MODE 1: Wo  -> fp32 out = v + bo[n] + resid32[m,n]
// MODE 2: FFN1-> bf16 out = gelu_tanh(v + b1[n]), stride 3072
// MODE 3: FFN2-> fp32 out = v + b2[n] + bf2f(residb[m,n])
// ---------------------------------------------------------------------------
template <int MODE, int BM, int BN>
__global__ __launch_bounds__(256) void gemm_bt(const u16* __restrict__ A,
                                               const u16* __restrict__ Bt,
                                               int K, int gx, int ntiles,
                                               const float* __restrict__ b0,
                                               const float* __restrict__ b1v,
                                               const float* __restrict__ b2v,
                                               const float* __restrict__ resid,
                                               const u16* __restrict__ residb,
                                               u16* __restrict__ ob0,
                                               u16* __restrict__ ob1,
                                               u16* __restrict__ ob2,
                                               float* __restrict__ of0) {
    constexpr int TM = BM / 32, TN = BN / 32;
    constexpr int BUF = (BM + BN) * 32;             // u16 elems per buffer
    constexpr int PF = BM / 64 + BN / 64;           // g2l16 per thread per chunk
    __shared__ __align__(16) u16 sm[3 * BUF];
    const int tid = threadIdx.x;
    const int lane = tid & 63;
    const int w = tid >> 6;
    const int wm = w & 1, wn = w >> 1;
    const int quad = lane >> 4, l15 = lane & 15;
    const int nb = gridDim.x;
    const int NI = K / 32;

    const int sr = tid >> 2;
    const int sq = ((tid & 3) ^ (sr & 3)) * 8;

    // staging cursor state
    int sTile = blockIdx.x, sKi = 0;
    const u16 *saP, *sbP;
    {
        const int ly = (sTile / (gx * 8)) * 8 + (sTile & 7);
        const int lx = (sTile >> 3) % gx;
        saP = A + (size_t)(ly * BM + sr) * K + sq;
        sbP = Bt + (size_t)(lx * BN + sr) * K + sq;
    }
    auto stageNext = [&](u16* dst) {
        if (sTile >= ntiles) return;
        const int k0 = sKi * 32;
#pragma unroll
        for (int j = 0; j < BM / 64; j++) g2l16(saP + (size_t)j * 64 * K + k0, dst + j * 2048 + tid * 8);
#pragma unroll
        for (int j = 0; j < BN / 64; j++) g2l16(sbP + (size_t)j * 64 * K + k0, dst + BM * 32 + j * 2048 + tid * 8);
        if (++sKi == NI) {
            sKi = 0; sTile += nb;
            if (sTile < ntiles) {
                const int ly = (sTile / (gx * 8)) * 8 + (sTile & 7);
                const int lx = (sTile >> 3) % gx;
                saP = A + (size_t)(ly * BM + sr) * K + sq;
                sbP = Bt + (size_t)(lx * BN + sr) * K + sq;
            }
        }
    };

    const int myTiles = (ntiles - 1 - (int)blockIdx.x) / nb + 1;
    const int totalChunks = myTiles * NI;

    // prologue: chunks 0,1 -> buffers 0,1
    stageNext(sm);
    stageNext(sm + BUF);

    int gc = 0;
    for (int cTile = blockIdx.x; cTile < ntiles; cTile += nb) {
        const int ly = (cTile / (gx * 8)) * 8 + (cTile & 7);
        const int lx = (cTile >> 3) % gx;
        const int mB = ly * BM, nB = lx * BN;
        f32x4 acc[TM][TN] = {};

        for (int i = 0; i < NI; ++i, ++gc) {
            if (gc + 1 < totalChunks) waitcnt_barrier<PF>();
            else                      waitcnt_barrier<0>();
            stageNext(sm + ((gc + 2) % 3) * BUF);
            const u16* As_ = sm + (gc % 3) * BUF;
            const u16* Bs_ = As_ + BM * 32;
            bf16x8 af[TM], bfr[TN];
#pragma unroll
            for (int t = 0; t < TM; t++) {
                const int rr = wm * (BM / 2) + t * 16 + l15;
                af[t] = *(const bf16x8*)&As_[rr * 32 + ((quad ^ (rr & 3)) * 8)];
            }
#pragma unroll
            for (int t = 0; t < TN; t++) {
                const int rn = wn * (BN / 2) + t * 16 + l15;
                bfr[t] = *(const bf16x8*)&Bs_[rn * 32 + ((quad ^ (rn & 3)) * 8)];
            }
#pragma unroll
            for (int mt = 0; mt < TM; mt++)
#pragma unroll
                for (int nt = 0; nt < TN; nt++)
                    acc[mt][nt] = __builtin_amdgcn_mfma_f32_16x16x32_bf16(af[mt], bfr[nt], acc[mt][nt], 0, 0, 0);
        }

        // epilogue (next tile's chunks already in flight)
#pragma unroll
        for (int mt = 0; mt < TM; mt++) {
#pragma unroll
            for (int nt = 0; nt < TN; nt++) {
                const int nc = nB + wn * (BN / 2) + nt * 16 + l15;
                const int mr0 = mB + wm * (BM / 2) + mt * 16 + quad * 4;
#pragma unroll
                for (int r = 0; r < 4; r++) {
                    float v = acc[mt][nt][r];
                    const size_t m = (size_t)(mr0 + r);
                    if constexpr (MODE == 0) {
                        if (nc < 768) {
                            ob0[m * 768 + nc] = f2bf_fast((v + b0[nc]) * SCALE_Q);
                        } else if (nc < 1536) {
                            ob1[m * 768 + (nc - 768)] = f2bf_fast(v + b1v[nc - 768]);
                        } else {
                            ob2[m * 768 + (nc - 1536)] = f2bf_fast(v + b2v[nc - 1536]);
                        }
                    } else if constexpr (MODE == 1) {
                        of0[m * 768 + nc] = v + b0[nc] + resid[m * 768 + nc];
                    } else if constexpr (MODE == 2) {
                        float g = v + b0[nc];
                        float z = g * (2.3025850930f + 0.1029407154f * g * g);
                        float t = exp2f_fast(z);
                        float th = 1.0f - 2.0f * __builtin_amdgcn_rcpf(t + 1.0f);
                        float hg = 0.5f * g;
                        ob0[m * 3072 + nc] = f2bf_fast(hg + hg * th);
                    } else {
                        of0[m * 768 + nc] = v + b0[nc] + bf2f(residb[m * 768 + nc]);
                    }
                }
            }
        }
    }
}

// ---------------------------------------------------------------------------
// Flash attention v5 — S^T formulation, register-resident P, XCD swizzle.
// (unchanged: 97% issue-saturated, near structural ceiling for this form)
// ---------------------------------------------------------------------------
__global__ __launch_bounds__(256) void flash_attn(const u16* __restrict__ q,
                                                  const u16* __restrict__ k,
                                                  const u16* __restrict__ vt,
                                                  u16* __restrict__ o) {
    __shared__ __align__(16) u16 smem[24576];      // 48 KB
    u16* Qs = smem + 16384;
    const int tid = threadIdx.x, lane = tid & 63, w = tid >> 6;
    const int quad = lane >> 4, l15 = lane & 15;

    const int id = blockIdx.y * 16 + blockIdx.x;
    const int bh = (id / 128) * 8 + (id & 7);
    const int qs0 = ((id >> 3) & 15) * 128;
    const int b = bh / 12, h = bh % 12;

#pragma unroll
    for (int j = 0; j < 4; j++) {
        int c = j * 256 + tid; int r = c >> 3, g = (c & 7) ^ (r & 7);
        g2l16(q + ((size_t)((qs0 + r) * 4 + b)) * 768 + h * 64 + g * 8, Qs + c * 8);
    }
#pragma unroll
    for (int j = 0; j < 2; j++) {
        int c = j * 256 + tid; int r = c >> 3, g = (c & 7) ^ (r & 7);
        g2l16(k + ((size_t)(r * 4 + b)) * 768 + h * 64 + g * 8, smem + c * 8);
        g2l16(vt + ((size_t)(bh * 64 + r)) * 2048 + g * 8, smem + 4096 + c * 8);
    }
    __syncthreads();

    s16x4 qf[2][4];
#pragma unroll
    for (int nt = 0; nt < 2; nt++) {
        const int qr = w * 32 + nt * 16 + l15;
#pragma unroll
        for (int ks = 0; ks < 4; ks++) {
            const int slot = (2 * ks + (quad >> 1)) ^ (qr & 7);
            qf[nt][ks] = bc<s16x4>(*(const uint2*)&Qs[qr * 64 + slot * 8 + (quad & 1) * 4]);
        }
    }

    f32x4 ot[4][2] = {};
    float l_acc[2] = { 0.0f, 0.0f };

    for (int it = 0; it < 32; ++it) {
        const u16* Kc = smem + (it & 1) * 8192;
        const u16* Vc = Kc + 4096;
        if (it < 31) {
            const int kv0n = (it + 1) * 64;
            u16* Kn = smem + ((it + 1) & 1) * 8192;
#pragma unroll
            for (int j = 0; j < 2; j++) {
                int c = j * 256 + tid; int r = c >> 3, g = (c & 7) ^ (r & 7);
                g2l16(k + ((size_t)((kv0n + r) * 4 + b)) * 768 + h * 64 + g * 8, Kn + c * 8);
                g2l16(vt + ((size_t)(bh * 64 + r)) * 2048 + kv0n + g * 8, Kn + 4096 + c * 8);
            }
        }

        f32x4 st[4][2] = {};
#pragma unroll
        for (int mt = 0; mt < 4; mt++) {
            const int kr = mt * 16 + l15;
            s16x4 kA[4];
#pragma unroll
            for (int ks = 0; ks < 4; ks++) {
                const int slot = (2 * ks + (quad >> 1)) ^ (kr & 7);
                kA[ks] = bc<s16x4>(*(const uint2*)&Kc[kr * 64 + slot * 8 + (quad & 1) * 4]);
            }
#pragma unroll
            for (int ks = 0; ks < 4; ks++)
#pragma unroll
                for (int nt = 0; nt < 2; nt++)
                    st[mt][nt] = mfma16(kA[ks], qf[nt][ks], st[mt][nt]);
        }

        s16x4 p[4][2];
#pragma unroll
        for (int mt = 0; mt < 4; mt++)
#pragma unroll
            for (int nt = 0; nt < 2; nt++) {
                float e0 = exp2f_fast(st[mt][nt][0]);
                float e1 = exp2f_fast(st[mt][nt][1]);
                float e2 = exp2f_fast(st[mt][nt][2]);
                float e3 = exp2f_fast(st[mt][nt][3]);
                l_acc[nt] += (e0 + e1) + (e2 + e3);
                p[mt][nt] = bc<s16x4>(make_uint2(pk_trunc(e0, e1), pk_trunc(e2, e3)));
            }

#pragma unroll
        for (int mt = 0; mt < 4; mt++)
#pragma unroll
            for (int md = 0; md < 4; md++) {
                const int vr = md * 16 + l15;
                const int slot = (2 * mt + (quad >> 1)) ^ (vr & 7);
                s16x4 vA = bc<s16x4>(*(const uint2*)&Vc[vr * 64 + slot * 8 + (quad & 1) * 4]);
#pragma unroll
                for (int nt = 0; nt < 2; nt++)
                    ot[md][nt] = mfma16(vA, p[mt][nt], ot[md][nt]);
            }
        __syncthreads();
    }

    float inv[2];
#pragma unroll
    for (int nt = 0; nt < 2; nt++) {
        float l = l_acc[nt];
        l += __shfl_xor(l, 16);
        l += __shfl_xor(l, 32);
        inv[nt] = 1.0f / l;
    }
#pragma unroll
    for (int md = 0; md < 4; md++)
#pragma unroll
        for (int nt = 0; nt < 2; nt++) {
            int qrow = qs0 + w * 32 + nt * 16 + l15;
            float iv = inv[nt];
            unsigned lo = pk_rne(ot[md][nt][0] * iv, ot[md][nt][1] * iv);
            unsigned hi = pk_rne(ot[md][nt][2] * iv, ot[md][nt][3] * iv);
            *(uint2*)(o + ((size_t)(qrow * 4 + b)) * 768 + h * 64 + md * 16 + quad * 4) =
                make_uint2(lo, hi);
        }
}

// ---------------------------------------------------------------------------
// launch
// ---------------------------------------------------------------------------
extern "C" void kernel_launch(void* const* d_in, const int* in_sizes, int n_in,
                              void* d_out, int out_size, void* d_ws, size_t ws_size,
                              hipStream_t stream) {
    const float* x   = (const float*)d_in[0];
    const float* Wq  = (const float*)d_in[3];
    const float* bq  = (const float*)d_in[4];
    const float* Wk  = (const float*)d_in[5];
    const float* bk  = (const float*)d_in[6];
    const float* Wv  = (const float*)d_in[7];
    const float* bv  = (const float*)d_in[8];
    const float* Wo  = (const float*)d_in[9];
    const float* bo  = (const float*)d_in[10];
    const float* g1  = (const float*)d_in[11];
    const float* be1 = (const float*)d_in[12];
    const float* W1  = (const float*)d_in[13];
    const float* b1  = (const float*)d_in[14];
    const float* W2  = (const float*)d_in[15];
    const float* b2  = (const float*)d_in[16];
    const float* g2  = (const float*)d_in[17];
    const float* be2 = (const float*)d_in[18];
    float* out = (float*)d_out;

    char* base = (char*)d_ws;
    u16*   WqkvT = (u16*)(base + 0);            // [2304][768]
    u16*   WoT   = (u16*)(base + 3538944);      // [768][768]
    u16*   W1T   = (u16*)(base + 4718592);      // [3072][768]
    u16*   W2T   = (u16*)(base + 9437184);      // [768][3072]
    u16*   xbf   = (u16*)(base + 14155776);     // [8192][768]   dead after QKV
    u16*   qb    = (u16*)(base + 26738688);     // dead after flash
    u16*   kb    = (u16*)(base + 39321600);     // dead after flash
    u16*   vb    = (u16*)(base + 51904512);     // dead after build_vt
    u16*   vtb   = (u16*)(base + 64487424);     // [48][64][2048] dead after flash
    u16*   attn  = (u16*)(base + 77070336);     // dead after Wo gemm
    float* r1    = (float*)(base + 14155776);   // fp32 [8192][768] aliases xbf+qb (dead)
    u16*   y1bf  = (u16*)(base + 114819072);    // [8192][768] bf16 (FFN1 in + FFN2 resid)
    u16*   hbuf  = (u16*)(base + 127401984);    // [8192][3072]
    // peak ws use: 177,733,632 B

    prep_all<<<13056, 256, 0, stream>>>(x, xbf, Wq, Wk, Wv, Wo, W1, W2,
                                        WqkvT, WoT, W1T, W2T);

    gemm_bt<0, 128, 128><<<576, 256, 0, stream>>>(xbf, WqkvT, 768, 18, 1152,
                                                  bq, bk, bv, nullptr, nullptr,
                                                  qb, kb, vb, nullptr);
    build_vt<<<dim3(32, 48), 256, 0, stream>>>(vb, vtb);
    flash_attn<<<dim3(16, 48), 256, 0, stream>>>(qb, kb, vtb, attn);
    gemm_bt<1, 64, 128><<<384, 256, 0, stream>>>(attn, WoT, 768, 6, 768,
                                                 bo, nullptr, nullptr, x, nullptr,
                                                 nullptr, nullptr, nullptr, r1);
    ln_kernel<<<8192, 256, 0, stream>>>(r1, g1, be1, nullptr, y1bf);
    gemm_bt<2, 128, 128><<<768, 256, 0, stream>>>(y1bf, W1T, 768, 24, 1536,
                                                  b1, nullptr, nullptr, nullptr, nullptr,
                                                  hbuf, nullptr, nullptr, nullptr);
    gemm_bt<3, 64, 128><<<768, 256, 0, stream>>>(hbuf, W2T, 3072, 6, 768,
                                                 b2, nullptr, nullptr, nullptr, y1bf,
                                                 nullptr, nullptr, nullptr, out);
    ln_kernel<<<8192, 256, 0, stream>>>(out, g2, be2, out, nullptr);
}

// Round 8
// 444.151 us; speedup vs baseline: 1.0783x; 1.0783x over previous
//
#include <hip/hip_runtime.h>
#include <cstdint>
#include <cstddef>

// ---------------------------------------------------------------------------
// EncoderLayer: x -> QKV -> MHA (flash) -> Wo + resid -> LN1 -> FFN(gelu) -> LN2
// S=2048 B=4 E=768 F=3072 H=12 Dh=64, M = S*B = 8192 tokens.
// R8: GEMM reverted to R5 structure (2-stage 32/24 KB LDS -> 5-6 blocks/CU;
//     prefetch-after-frag-reads + __syncthreads). Flash LDS 48->32 KB by
//     staging Q through the K/V buffer space -> 5 blocks/CU (was 3).
//     Kept from R7: prep_all fusion, LN1 bf16-only, FFN2 bf16 residual.
// ---------------------------------------------------------------------------

typedef unsigned short u16;
typedef __bf16 bf16x8 __attribute__((ext_vector_type(8)));
typedef __bf16 bf16x4 __attribute__((ext_vector_type(4)));
typedef short  s16x4  __attribute__((ext_vector_type(4)));
typedef float  f32x4  __attribute__((ext_vector_type(4)));

#define SCALE_Q 0.18033688011112042f   // 0.125 * log2(e)

__device__ __forceinline__ unsigned fbits(float f) { union { float f; unsigned u; } v; v.f = f; return v.u; }
__device__ __forceinline__ u16 f2bf_fast(float f) { return (u16)((fbits(f) + 0x8000u) >> 16); }
__device__ __forceinline__ float bf2f(u16 u) { union { unsigned u; float f; } v; v.u = (unsigned)u << 16; return v.f; }
__device__ __forceinline__ unsigned pk_rne(float a, float b) {
    return __builtin_amdgcn_perm(fbits(b) + 0x8000u, fbits(a) + 0x8000u, 0x07060302u);
}
__device__ __forceinline__ unsigned pk_trunc(float a, float b) {
    return __builtin_amdgcn_perm(fbits(b), fbits(a), 0x07060302u);
}
__device__ __forceinline__ float exp2f_fast(float x) {
#if __has_builtin(__builtin_amdgcn_exp2f)
    return __builtin_amdgcn_exp2f(x);
#else
    return __expf(x * 0.69314718055994531f);
#endif
}

template <class T, class F>
__device__ __forceinline__ T bc(F f) { union { F a; T b; } u; u.a = f; return u.b; }

__device__ __forceinline__ f32x4 mfma16(s16x4 a, s16x4 b, f32x4 c) {
#if __has_builtin(__builtin_amdgcn_mfma_f32_16x16x16_bf16)
    return __builtin_amdgcn_mfma_f32_16x16x16_bf16(
        __builtin_bit_cast(bf16x4, a), __builtin_bit_cast(bf16x4, b), c, 0, 0, 0);
#else
    return __builtin_amdgcn_mfma_f32_16x16x16bf16_1k(a, b, c, 0, 0, 0);
#endif
}

__device__ __forceinline__ void g2l16(const void* g, void* l) {
    __builtin_amdgcn_global_load_lds(
        (const __attribute__((address_space(1))) unsigned int*)(uintptr_t)g,
        (__attribute__((address_space(3))) unsigned int*)(unsigned int)(uintptr_t)l,
        16, 0, 0);
}

// barrier after this wave's LDS reads have retired (no vmem drain needed)
__device__ __forceinline__ void lgkm_barrier() {
    asm volatile("s_waitcnt lgkmcnt(0)\ns_barrier" ::: "memory");
}

// ---------------------------------------------------------------------------
// prep_all: 5 weight transposes (fp32 [Kd][Nd] -> bf16 [Nd][Kd]) + x cvt.
// ---------------------------------------------------------------------------
__global__ __launch_bounds__(256) void prep_all(const float* __restrict__ x, u16* __restrict__ xbf,
                                                const float* __restrict__ Wq, const float* __restrict__ Wk,
                                                const float* __restrict__ Wv, const float* __restrict__ Wo,
                                                const float* __restrict__ W1, const float* __restrict__ W2,
                                                u16* __restrict__ WqkvT, u16* __restrict__ WoT,
                                                u16* __restrict__ W1T, u16* __restrict__ W2T) {
    const int id = blockIdx.x;
    if (id >= 6912) {                      // x: fp32 -> bf16, 6144 blocks
        int i = (id - 6912) * 256 + threadIdx.x;
        float4 v = ((const float4*)x)[i];
        ((uint2*)xbf)[i] = make_uint2(pk_rne(v.x, v.y), pk_rne(v.z, v.w));
        return;
    }
    const float* src; u16* dst; int Kd, Nd, bx, by, l;
    if (id < 576)       { src = Wq; dst = WqkvT;             Kd = 768;  Nd = 768;  l = id;        bx = l % 24; by = l / 24; }
    else if (id < 1152) { src = Wk; dst = WqkvT + 768 * 768; Kd = 768;  Nd = 768;  l = id - 576;  bx = l % 24; by = l / 24; }
    else if (id < 1728) { src = Wv; dst = WqkvT + 1536 * 768;Kd = 768;  Nd = 768;  l = id - 1152; bx = l % 24; by = l / 24; }
    else if (id < 2304) { src = Wo; dst = WoT;               Kd = 768;  Nd = 768;  l = id - 1728; bx = l % 24; by = l / 24; }
    else if (id < 4608) { src = W1; dst = W1T;               Kd = 768;  Nd = 3072; l = id - 2304; bx = l % 96; by = l / 96; }
    else                { src = W2; dst = W2T;               Kd = 3072; Nd = 768;  l = id - 4608; bx = l % 24; by = l / 24; }
    __shared__ float t[32][33];
    const int k0 = by * 32, n0 = bx * 32;
    const int tx = threadIdx.x & 31, ty = threadIdx.x >> 5;
#pragma unroll
    for (int i = 0; i < 32; i += 8)
        t[ty + i][tx] = src[(size_t)(k0 + ty + i) * Nd + n0 + tx];
    __syncthreads();
#pragma unroll
    for (int i = 0; i < 32; i += 8)
        dst[(size_t)(n0 + ty + i) * Kd + k0 + tx] = f2bf_fast(t[tx][ty + i]);
}

// ---------------------------------------------------------------------------
// build VT[bh][d][s] (bf16) from v [m = s*4+b][h*64+d]
// ---------------------------------------------------------------------------
__global__ __launch_bounds__(256) void build_vt(const u16* __restrict__ v,
                                                u16* __restrict__ vt) {
    __shared__ u16 t[64][65];
    const int bh = blockIdx.y, b = bh / 12, h = bh % 12;
    const int s0 = blockIdx.x * 64;
    const int tid = threadIdx.x;
#pragma unroll
    for (int i = 0; i < 16; i++) {
        int c = i * 256 + tid; int r = c >> 6, d = c & 63;
        t[r][d] = v[((size_t)((s0 + r) * 4 + b)) * 768 + h * 64 + d];
    }
    __syncthreads();
#pragma unroll
    for (int i = 0; i < 16; i++) {
        int c = i * 256 + tid; int dr = c >> 6, s = c & 63;
        vt[((size_t)(bh * 64 + dr)) * 2048 + s0 + s] = t[s][dr];
    }
}

// ---------------------------------------------------------------------------
// LayerNorm over E=768. One block (256 thr) per row.
// ---------------------------------------------------------------------------
__global__ __launch_bounds__(256) void ln_kernel(const float* __restrict__ in,
                                                 const float* __restrict__ gw,
                                                 const float* __restrict__ bw,
                                                 float* __restrict__ of32,
                                                 u16* __restrict__ obf) {
    const int row = blockIdx.x;
    const int tid = threadIdx.x;
    const int lane = tid & 63, w = tid >> 6;
    const float* xr = in + (size_t)row * 768;
    float v0 = xr[tid], v1 = xr[tid + 256], v2 = xr[tid + 512];
    float s = v0 + v1 + v2;
    float s2 = v0 * v0 + v1 * v1 + v2 * v2;
#pragma unroll
    for (int o = 32; o > 0; o >>= 1) { s += __shfl_down(s, o); s2 += __shfl_down(s2, o); }
    __shared__ float red[8];
    if (lane == 0) { red[w] = s; red[4 + w] = s2; }
    __syncthreads();
    s  = red[0] + red[1] + red[2] + red[3];
    s2 = red[4] + red[5] + red[6] + red[7];
    const float mean = s * (1.0f / 768.0f);
    const float rstd = rsqrtf(s2 * (1.0f / 768.0f) - mean * mean + 1e-5f);
    float va[3] = { v0, v1, v2 };
#pragma unroll
    for (int i = 0; i < 3; i++) {
        int j = tid + i * 256;
        float y = (va[i] - mean) * rstd * gw[j] + bw[j];
        if (of32) of32[(size_t)row * 768 + j] = y;
        if (obf)  obf [(size_t)row * 768 + j] = f2bf_fast(y);
    }
}

// ---------------------------------------------------------------------------
// GEMM (R5 structure): C[M,N] = A[M,K] * Bt[N,K]^T, bf16 in, fp32 acc.
// BM x BN tile, BK=32, 4 waves (2x2). 2-stage LDS dbuf (32/24 KB -> 5-6
// blocks/CU), prefetch issued after frag reads, __syncthreads per iter.
// XCD swizzle: id%8 -> row-block pinned per XCD (B-tiles L2-resident).
// MODE 0: QKV -> q=(v+bq)*SCALE_Q / k=v+bk / v=v+bv, bf16 out [m][768] each
// MODE 1: Wo  -> fp32 out = v + bo[n] + resid32[m,n]
// MODE 2: FFN1-> bf16 out = gelu_tanh(v + b1[n]), stride 3072
// MODE 3: FFN2-> fp32 out = v + b2[n] + bf2f(residb[m,n])
// ---------------------------------------------------------------------------
template <int MODE, int BM, int BN>
__global__ __launch_bounds__(256) void gemm_bt(const u16* __restrict__ A,
                                               const u16* __restrict__ Bt, int K,
                                               const float* __restrict__ b0,
                                               const float* __restrict__ b1v,
                                               const float* __restrict__ b2v,
                                               const float* __restrict__ resid,
                                               const u16* __restrict__ residb,
                                               u16* __restrict__ ob0,
                                               u16* __restrict__ ob1,
                                               u16* __restrict__ ob2,
                                               float* __restrict__ of0) {
    constexpr int TM = BM / 32, TN = BN / 32;
    constexpr int BUF = (BM + BN) * 32;             // u16 elems per buffer
    __shared__ __align__(16) u16 sm[2 * BUF];
    const int tid = threadIdx.x;
    const int lane = tid & 63;
    const int w = tid >> 6;
    const int wm = w & 1, wn = w >> 1;
    const int quad = lane >> 4, l15 = lane & 15;

    // ---- XCD-locality swizzle (id%8 -> same row-block on one XCD)
    const int gx = gridDim.x;
    const int id = blockIdx.y * gx + blockIdx.x;
    const int ly = (id / (gx * 8)) * 8 + (id & 7);
    const int lx = (id >> 3) % gx;
    const int mBase = ly * BM;
    const int nBase = lx * BN;

    const int sr = tid >> 2;
    const int sq = ((tid & 3) ^ (sr & 3)) * 8;
    const u16* aP = A + (size_t)(mBase + sr) * K + sq;
    const u16* bP = Bt + (size_t)(nBase + sr) * K + sq;

    f32x4 acc[TM][TN] = {};
    const int NI = K / 32;

    // stage tile 0 into buffer 0
#pragma unroll
    for (int j = 0; j < BM / 64; j++) g2l16(aP + (size_t)j * 64 * K, sm + j * 2048 + tid * 8);
#pragma unroll
    for (int j = 0; j < BN / 64; j++) g2l16(bP + (size_t)j * 64 * K, sm + BM * 32 + j * 2048 + tid * 8);
    __syncthreads();

    for (int i = 0; i < NI; ++i) {
        const u16* As_ = sm + (i & 1) * BUF;
        const u16* Bs_ = As_ + BM * 32;
        bf16x8 af[TM], bfr[TN];
#pragma unroll
        for (int t = 0; t < TM; t++) {
            const int rr = wm * (BM / 2) + t * 16 + l15;
            af[t] = *(const bf16x8*)&As_[rr * 32 + ((quad ^ (rr & 3)) * 8)];
        }
#pragma unroll
        for (int t = 0; t < TN; t++) {
            const int rn = wn * (BN / 2) + t * 16 + l15;
            bfr[t] = *(const bf16x8*)&Bs_[rn * 32 + ((quad ^ (rn & 3)) * 8)];
        }
        if (i + 1 < NI) {                           // prefetch tile i+1
            u16* dst = sm + ((i + 1) & 1) * BUF;
            const int k0 = (i + 1) * 32;
#pragma unroll
            for (int j = 0; j < BM / 64; j++) g2l16(aP + (size_t)j * 64 * K + k0, dst + j * 2048 + tid * 8);
#pragma unroll
            for (int j = 0; j < BN / 64; j++) g2l16(bP + (size_t)j * 64 * K + k0, dst + BM * 32 + j * 2048 + tid * 8);
        }
#pragma unroll
        for (int mt = 0; mt < TM; mt++)
#pragma unroll
            for (int nt = 0; nt < TN; nt++)
                acc[mt][nt] = __builtin_amdgcn_mfma_f32_16x16x32_bf16(af[mt], bfr[nt], acc[mt][nt], 0, 0, 0);
        __syncthreads();
    }

#pragma unroll
    for (int mt = 0; mt < TM; mt++) {
#pragma unroll
        for (int nt = 0; nt < TN; nt++) {
            const int nc = nBase + wn * (BN / 2) + nt * 16 + l15;
            const int mr0 = mBase + wm * (BM / 2) + mt * 16 + quad * 4;
#pragma unroll
            for (int r = 0; r < 4; r++) {
                float v = acc[mt][nt][r];
                const size_t m = (size_t)(mr0 + r);
                if constexpr (MODE == 0) {
                    if (nc < 768) {
                        ob0[m * 768 + nc] = f2bf_fast((v + b0[nc]) * SCALE_Q);
                    } else if (nc < 1536) {
                        ob1[m * 768 + (nc - 768)] = f2bf_fast(v + b1v[nc - 768]);
                    } else {
                        ob2[m * 768 + (nc - 1536)] = f2bf_fast(v + b2v[nc - 1536]);
                    }
                } else if constexpr (MODE == 1) {
                    of0[m * 768 + nc] = v + b0[nc] + resid[m * 768 + nc];
                } else if constexpr (MODE == 2) {
                    float g = v + b0[nc];
                    float z = g * (2.3025850930f + 0.1029407154f * g * g);
                    float t = exp2f_fast(z);
                    float th = 1.0f - 2.0f * __builtin_amdgcn_rcpf(t + 1.0f);
                    float hg = 0.5f * g;
                    ob0[m * 3072 + nc] = f2bf_fast(hg + hg * th);
                } else {
                    of0[m * 768 + nc] = v + b0[nc] + bf2f(residb[m * 768 + nc]);
                }
            }
        }
    }
}

// ---------------------------------------------------------------------------
// Flash attention v6 — S^T formulation, register-resident P, XCD swizzle,
// 32 KB LDS (Q staged through the K/V buffer space; Q frags live in regs)
// -> 5 blocks/CU (was 3). Inner loop identical to v5.
// ---------------------------------------------------------------------------
__global__ __launch_bounds__(256) void flash_attn(const u16* __restrict__ q,
                                                  const u16* __restrict__ k,
                                                  const u16* __restrict__ vt,
                                                  u16* __restrict__ o) {
    __shared__ __align__(16) u16 smem[16384];      // 32 KB: buf i at i*8192 (K,V)
    const int tid = threadIdx.x, lane = tid & 63, w = tid >> 6;
    const int quad = lane >> 4, l15 = lane & 15;

    const int id = blockIdx.y * 16 + blockIdx.x;
    const int bh = (id / 128) * 8 + (id & 7);
    const int qs0 = ((id >> 3) & 15) * 128;
    const int b = bh / 12, h = bh % 12;

    // ---- stage Q [128][64] through the whole 32 KB (16 KB used), swizzled
#pragma unroll
    for (int j = 0; j < 4; j++) {
        int c = j * 256 + tid; int r = c >> 3, g = (c & 7) ^ (r & 7);
        g2l16(q + ((size_t)((qs0 + r) * 4 + b)) * 768 + h * 64 + g * 8, smem + c * 8);
    }
    __syncthreads();                               // Q in LDS

    // ---- Q B-fragments (lane n=q=l15, k=d=ks*16+quad*4+j) cached for all iters
    s16x4 qf[2][4];
#pragma unroll
    for (int nt = 0; nt < 2; nt++) {
        const int qr = w * 32 + nt * 16 + l15;
#pragma unroll
        for (int ks = 0; ks < 4; ks++) {
            const int slot = (2 * ks + (quad >> 1)) ^ (qr & 7);
            qf[nt][ks] = bc<s16x4>(*(const uint2*)&smem[qr * 64 + slot * 8 + (quad & 1) * 4]);
        }
    }
    lgkm_barrier();                                // all waves done reading Q

    // ---- stage K/V tile 0 -> buf0, tile 1 -> buf1
#pragma unroll
    for (int it0 = 0; it0 < 2; it0++) {
        u16* dst = smem + it0 * 8192;
        const int kv0 = it0 * 64;
#pragma unroll
        for (int j = 0; j < 2; j++) {
            int c = j * 256 + tid; int r = c >> 3, g = (c & 7) ^ (r & 7);
            g2l16(k + ((size_t)((kv0 + r) * 4 + b)) * 768 + h * 64 + g * 8, dst + c * 8);
            g2l16(vt + ((size_t)(bh * 64 + r)) * 2048 + kv0 + g * 8, dst + 4096 + c * 8);
        }
    }
    __syncthreads();                               // bufs 0,1 ready

    f32x4 ot[4][2] = {};
    float l_acc[2] = { 0.0f, 0.0f };

    for (int it = 0; it < 32; ++it) {
        const u16* Kc = smem + (it & 1) * 8192;
        const u16* Vc = Kc + 4096;
        if (it < 30) {                             // prefetch tile it+2 into buf being freed next
            const int kv0n = (it + 2) * 64;
            u16* Kn = smem + (it & 1) * 8192;      // NOTE: overwritten AFTER this iter's reads? No -
            Kn = smem + ((it + 2) & 1) * 8192;     // (it+2)&1 == it&1: same buffer as current!
            // -> must NOT overwrite current buffer mid-iteration. Prefetch is
            // issued here but the DMA writes complete only after the end-of-iter
            // __syncthreads (vmcnt(0) drain) -- incorrect. Use it+1 scheme:
        }
        if (it < 31 && false) {}
        // standard it+1 prefetch into the other buffer (R5 scheme)
        if (it < 30) {
            const int kv0n = (it + 2) * 64;
            (void)kv0n;
        }
        if (it >= 1) {}                            // (dead code kept minimal below)

        // ---- S^T = K.Q^T
        f32x4 st[4][2] = {};
#pragma unroll
        for (int mt = 0; mt < 4; mt++) {
            const int kr = mt * 16 + l15;
            s16x4 kA[4];
#pragma unroll
            for (int ks = 0; ks < 4; ks++) {
                const int slot = (2 * ks + (quad >> 1)) ^ (kr & 7);
                kA[ks] = bc<s16x4>(*(const uint2*)&Kc[kr * 64 + slot * 8 + (quad & 1) * 4]);
            }
#pragma unroll
            for (int ks = 0; ks < 4; ks++)
#pragma unroll
                for (int nt = 0; nt < 2; nt++)
                    st[mt][nt] = mfma16(kA[ks], qf[nt][ks], st[mt][nt]);
        }

        // ---- P = 2^(S'), pack via v_perm, accumulate denominator
        s16x4 p[4][2];
#pragma unroll
        for (int mt = 0; mt < 4; mt++)
#pragma unroll
            for (int nt = 0; nt < 2; nt++) {
                float e0 = exp2f_fast(st[mt][nt][0]);
                float e1 = exp2f_fast(st[mt][nt][1]);
                float e2 = exp2f_fast(st[mt][nt][2]);
                float e3 = exp2f_fast(st[mt][nt][3]);
                l_acc[nt] += (e0 + e1) + (e2 + e3);
                p[mt][nt] = bc<s16x4>(make_uint2(pk_trunc(e0, e1), pk_trunc(e2, e3)));
            }

        // ---- O^T += V^T.P^T
#pragma unroll
        for (int mt = 0; mt < 4; mt++)
#pragma unroll
            for (int md = 0; md < 4; md++) {
                const int vr = md * 16 + l15;
                const int slot = (2 * mt + (quad >> 1)) ^ (vr & 7);
                s16x4 vA = bc<s16x4>(*(const uint2*)&Vc[vr * 64 + slot * 8 + (quad & 1) * 4]);
#pragma unroll
                for (int nt = 0; nt < 2; nt++)
                    ot[md][nt] = mfma16(vA, p[mt][nt], ot[md][nt]);
            }

        lgkm_barrier();                            // this block's waves done with buf (it&1)
        if (it < 30) {                             // refill the just-freed buffer with tile it+2
            const int kv0n = (it + 2) * 64;
            u16* Kn = smem + (it & 1) * 8192;
#pragma unroll
            for (int j = 0; j < 2; j++) {
                int c = j * 256 + tid; int r = c >> 3, g = (c & 7) ^ (r & 7);
                g2l16(k + ((size_t)((kv0n + r) * 4 + b)) * 768 + h * 64 + g * 8, Kn + c * 8);
                g2l16(vt + ((size_t)(bh * 64 + r)) * 2048 + kv0n + g * 8, Kn + 4096 + c * 8);
            }
        }
        __syncthreads();                           // drain: buf (it+1)&1 ready for next iter
    }

    float inv[2];
#pragma unroll
    for (int nt = 0; nt < 2; nt++) {
        float l = l_acc[nt];
        l += __shfl_xor(l, 16);
        l += __shfl_xor(l, 32);
        inv[nt] = 1.0f / l;
    }
#pragma unroll
    for (int md = 0; md < 4; md++)
#pragma unroll
        for (int nt = 0; nt < 2; nt++) {
            int qrow = qs0 + w * 32 + nt * 16 + l15;
            float iv = inv[nt];
            unsigned lo = pk_rne(ot[md][nt][0] * iv, ot[md][nt][1] * iv);
            unsigned hi = pk_rne(ot[md][nt][2] * iv, ot[md][nt][3] * iv);
            *(uint2*)(o + ((size_t)(qrow * 4 + b)) * 768 + h * 64 + md * 16 + quad * 4) =
                make_uint2(lo, hi);
        }
}

// ---------------------------------------------------------------------------
// launch
// ---------------------------------------------------------------------------
extern "C" void kernel_launch(void* const* d_in, const int* in_sizes, int n_in,
                              void* d_out, int out_size, void* d_ws, size_t ws_size,
                              hipStream_t stream) {
    const float* x   = (const float*)d_in[0];
    const float* Wq  = (const float*)d_in[3];
    const float* bq  = (const float*)d_in[4];
    const float* Wk  = (const float*)d_in[5];
    const float* bk  = (const float*)d_in[6];
    const float* Wv  = (const float*)d_in[7];
    const float* bv  = (const float*)d_in[8];
    const float* Wo  = (const float*)d_in[9];
    const float* bo  = (const float*)d_in[10];
    const float* g1  = (const float*)d_in[11];
    const float* be1 = (const float*)d_in[12];
    const float* W1  = (const float*)d_in[13];
    const float* b1  = (const float*)d_in[14];
    const float* W2  = (const float*)d_in[15];
    const float* b2  = (const float*)d_in[16];
    const float* g2  = (const float*)d_in[17];
    const float* be2 = (const float*)d_in[18];
    float* out = (float*)d_out;

    char* base = (char*)d_ws;
    u16*   WqkvT = (u16*)(base + 0);            // [2304][768]
    u16*   WoT   = (u16*)(base + 3538944);      // [768][768]
    u16*   W1T   = (u16*)(base + 4718592);      // [3072][768]
    u16*   W2T   = (u16*)(base + 9437184);      // [768][3072]
    u16*   xbf   = (u16*)(base + 14155776);     // [8192][768]   dead after QKV
    u16*   qb    = (u16*)(base + 26738688);     // dead after flash
    u16*   kb    = (u16*)(base + 39321600);     // dead after flash
    u16*   vb    = (u16*)(base + 51904512);     // dead after build_vt
    u16*   vtb   = (u16*)(base + 64487424);     // [48][64][2048] dead after flash
    u16*   attn  = (u16*)(base + 77070336);     // dead after Wo gemm
    float* r1    = (float*)(base + 14155776);   // fp32 [8192][768] aliases xbf+qb (dead)
    u16*   y1bf  = (u16*)(base + 114819072);    // [8192][768] bf16 (FFN1 in + FFN2 resid)
    u16*   hbuf  = (u16*)(base + 127401984);    // [8192][3072]
    // peak ws use: 177,733,632 B

    prep_all<<<13056, 256, 0, stream>>>(x, xbf, Wq, Wk, Wv, Wo, W1, W2,
                                        WqkvT, WoT, W1T, W2T);

    gemm_bt<0, 128, 128><<<dim3(18, 64), 256, 0, stream>>>(xbf, WqkvT, 768,
                                                           bq, bk, bv, nullptr, nullptr,
                                                           qb, kb, vb, nullptr);
    build_vt<<<dim3(32, 48), 256, 0, stream>>>(vb, vtb);
    flash_attn<<<dim3(16, 48), 256, 0, stream>>>(qb, kb, vtb, attn);
    gemm_bt<1, 64, 128><<<dim3(6, 128), 256, 0, stream>>>(attn, WoT, 768,
                                                          bo, nullptr, nullptr, x, nullptr,
                                                          nullptr, nullptr, nullptr, r1);
    ln_kernel<<<8192, 256, 0, stream>>>(r1, g1, be1, nullptr, y1bf);
    gemm_bt<2, 128, 128><<<dim3(24, 64), 256, 0, stream>>>(y1bf, W1T, 768,
                                                           b1, nullptr, nullptr, nullptr, nullptr,
                                                           hbuf, nullptr, nullptr, nullptr);
    gemm_bt<3, 64, 128><<<dim3(6, 128), 256, 0, stream>>>(hbuf, W2T, 3072,
                                                          b2, nullptr, nullptr, nullptr, y1bf,
                                                          nullptr, nullptr, nullptr, out);
    ln_kernel<<<8192, 256, 0, stream>>>(out, g2, be2, out, nullptr);
}